// Round 1
// 1101.675 us; speedup vs baseline: 1.0394x; 1.0394x over previous
//
#include <hip/hip_runtime.h>
#include <hip/hip_bf16.h>
#include <math.h>

// Problem constants
constexpr int kB = 256, kS = 20, kE = 128, kH = 256;
constexpr int kTotalW = 2768;           // 432+16 + 2304+16
constexpr float kSlope = 1.0f / 5.5f;

typedef __bf16 bf16x8 __attribute__((ext_vector_type(8)));
typedef float  floatx4 __attribute__((ext_vector_type(4)));

// ---------------------------------------------------------------------------
// zero-fill (ws is poisoned 0xAA every call)
__global__ void zero_f32(float* __restrict__ p, int n) {
    for (int i = blockIdx.x * blockDim.x + threadIdx.x; i < n; i += gridDim.x * blockDim.x)
        p[i] = 0.f;
}

// rowmajor fp32 -> bf16 (RNE)
__global__ void cvt_bf16(const float* __restrict__ in, __bf16* __restrict__ out, int n) {
    for (int i = blockIdx.x * blockDim.x + threadIdx.x; i < n; i += gridDim.x * blockDim.x)
        out[i] = (__bf16)in[i];
}

// W (K x N fp32, row-major) -> Wt (N x K bf16, row-major). grid (K/32, ceil(N/32)), block 256.
__global__ __launch_bounds__(256) void transpose_cvt(
    const float* __restrict__ W, __bf16* __restrict__ Wt, int K, int N) {
    __shared__ float t[32][33];
    const int k0 = blockIdx.x * 32, n0 = blockIdx.y * 32;
    const int tx = threadIdx.x & 31, ty = threadIdx.x >> 5;   // 32 x 8
#pragma unroll
    for (int j = 0; j < 32; j += 8) {
        int n = n0 + tx, k = k0 + ty + j;
        t[ty + j][tx] = (n < N) ? W[(size_t)k * N + n] : 0.f;
    }
    __syncthreads();
#pragma unroll
    for (int j = 0; j < 32; j += 8) {
        int n = n0 + ty + j, k = k0 + tx;
        if (n < N) Wt[(size_t)n * K + k] = (__bf16)t[tx][ty + j];
    }
}

// ---------------------------------------------------------------------------
// async 16B global -> LDS (direct-to-LDS DMA; dest = wave-uniform base + lane*16)
__device__ __forceinline__ void gload16(const __bf16* g, __bf16* l) {
    __builtin_amdgcn_global_load_lds(
        (const __attribute__((address_space(1))) void*)g,
        (__attribute__((address_space(3))) void*)l, 16, 0, 0);
}

// ---------------------------------------------------------------------------
// bf16 MFMA split-K GEMM, m97 structure: 128x128 tile, BK=64, global_load_lds
// width-16 staging, single-buffer 2-barrier K-loop.
// Cacc(M,N fp32, pre-zeroed) += A(MxK bf16) @ Bt(NxK bf16)^T.
// 4 waves in a 2x2 grid, each wave owns a 64x64 sub-tile (acc[4][4] of 16x16).
// Fragment layouts (verified): A/B [outer=lane&15][k=(lane>>4)*8+j],
// C/D col=lane&15, row=(lane>>4)*4+reg.
// LDS linear [128][64] bf16 (no pad: global_load_lds needs contiguous dest).
// N not multiple of 128 handled by clamping B gather row (dup reads, garbage
// acc columns never stored). M, K must be multiples of 128/64 (true here).
__global__ __launch_bounds__(256) void mfma128(
    const __bf16* __restrict__ A, const __bf16* __restrict__ Bt,
    float* __restrict__ Cacc, int M, int N, int K, int Kchunk) {
    __shared__ __bf16 As[128 * 64];
    __shared__ __bf16 Bs[128 * 64];
    const int m0 = blockIdx.x * 128, n0 = blockIdx.y * 128;
    const int kbeg = blockIdx.z * Kchunk, kend = kbeg + Kchunk;
    const int tid = threadIdx.x, lane = tid & 63, wave = tid >> 6;
    const int wr = (wave >> 1) * 64, wc = (wave & 1) * 64;
    const int srow = lane >> 3, scol = (lane & 7) * 8;   // staging: lane -> (row, 16B seg)
    const int lrow = lane & 15, lk = (lane >> 4) * 8;    // frag read offsets
    floatx4 acc[4][4] = {};

    for (int k0 = kbeg; k0 < kend; k0 += 64) {
        // stage A/B 128x64 tiles: 8 chunks/wave, 1 KiB (8 rows) each, direct to LDS
#pragma unroll
        for (int c = 0; c < 4; ++c) {
            const int ch = wave * 4 + c;           // chunk 0..15 -> rows ch*8..ch*8+7
            const int rr = ch * 8 + srow;
            gload16(A + (size_t)(m0 + rr) * K + k0 + scol, &As[ch * 512]);
            int nr = n0 + rr; if (nr > N - 1) nr = N - 1;
            gload16(Bt + (size_t)nr * K + k0 + scol, &Bs[ch * 512]);
        }
        __syncthreads();                            // drains vmcnt -> tiles ready
#pragma unroll
        for (int ks = 0; ks < 2; ++ks) {
            bf16x8 af[4], bfv[4];
#pragma unroll
            for (int m = 0; m < 4; ++m)
                af[m] = *(const bf16x8*)&As[(wr + m * 16 + lrow) * 64 + ks * 32 + lk];
#pragma unroll
            for (int n = 0; n < 4; ++n)
                bfv[n] = *(const bf16x8*)&Bs[(wc + n * 16 + lrow) * 64 + ks * 32 + lk];
#pragma unroll
            for (int m = 0; m < 4; ++m)
#pragma unroll
                for (int n = 0; n < 4; ++n)
                    acc[m][n] = __builtin_amdgcn_mfma_f32_16x16x32_bf16(
                        af[m], bfv[n], acc[m][n], 0, 0, 0);
        }
        __syncthreads();
    }
    const int col = lane & 15, rq = (lane >> 4) * 4;
#pragma unroll
    for (int m = 0; m < 4; ++m)
#pragma unroll
        for (int n = 0; n < 4; ++n)
#pragma unroll
            for (int r = 0; r < 4; ++r) {
                int gm = m0 + wr + m * 16 + rq + r, gn = n0 + wc + n * 16 + col;
                if (gn < N) atomicAdd(&Cacc[(size_t)gm * N + gn], acc[m][n][r]);
            }
}

// epilogues: bias + leaky-relu -> bf16 (feeds next MFMA GEMM) / bias only -> fp32
__global__ void ep_lrelu_bf16(const float* __restrict__ acc, const float* __restrict__ bias,
                              __bf16* __restrict__ out, int M, int N) {
    int i = blockIdx.x * blockDim.x + threadIdx.x;
    if (i < M * N) {
        float v = acc[i] + bias[i % N];
        out[i] = (__bf16)(v > 0.f ? v : v * kSlope);
    }
}
__global__ void ep_bias_f32(const float* __restrict__ acc, const float* __restrict__ bias,
                            float* __restrict__ out, int M, int N) {
    int i = blockIdx.x * blockDim.x + threadIdx.x;
    if (i < M * N) out[i] = acc[i] + bias[i % N];
}

// ---------------------------------------------------------------------------
// xih via MFMA: xih[(s*B+b)*4H + n] = embb[q[b,s]] . w_ihb[n,:] + b_ih[n] + b_hh[n]
// A rows gathered via qs; w_ihb (4H x E) row-major == Bt layout. grid (80,16).
__global__ __launch_bounds__(256) void xih_mfma(
    const int* __restrict__ questions, const __bf16* __restrict__ embb,
    const __bf16* __restrict__ w_ihb, const float* __restrict__ b_ih,
    const float* __restrict__ b_hh, float* __restrict__ xih) {
    __shared__ __bf16 As[64][72];
    __shared__ __bf16 Bs[64][72];
    __shared__ int qs[64];
    const int m0 = blockIdx.x * 64, n0 = blockIdx.y * 64;
    const int tid = threadIdx.x, lane = tid & 63, wave = tid >> 6;
    if (tid < 64) {
        int m = m0 + tid;
        qs[tid] = questions[(m % kB) * kS + (m / kB)];
    }
    __syncthreads();
    floatx4 acc[4] = {};
    for (int k0 = 0; k0 < kE; k0 += 64) {
        for (int i = tid; i < 512; i += 256) {
            int r = i >> 3, seg = i & 7;
            *(uint4*)(&As[r][seg * 8]) =
                *(const uint4*)(embb + (size_t)qs[r] * kE + k0 + seg * 8);
        }
        for (int i = tid; i < 512; i += 256) {
            int r = i >> 3, seg = i & 7;
            *(uint4*)(&Bs[r][seg * 8]) =
                *(const uint4*)(w_ihb + (size_t)(n0 + r) * kE + k0 + seg * 8);
        }
        __syncthreads();
#pragma unroll
        for (int ks = 0; ks < 2; ++ks) {
            bf16x8 af = *(const bf16x8*)(&As[wave * 16 + (lane & 15)][ks * 32 + (lane >> 4) * 8]);
#pragma unroll
            for (int nb = 0; nb < 4; ++nb) {
                bf16x8 bfr = *(const bf16x8*)(&Bs[nb * 16 + (lane & 15)][ks * 32 + (lane >> 4) * 8]);
                acc[nb] = __builtin_amdgcn_mfma_f32_16x16x32_bf16(af, bfr, acc[nb], 0, 0, 0);
            }
        }
        __syncthreads();
    }
    const int col = lane & 15, rq = (lane >> 4) * 4;
#pragma unroll
    for (int nb = 0; nb < 4; ++nb)
#pragma unroll
        for (int r = 0; r < 4; ++r) {
            int m = m0 + wave * 16 + rq + r, n = n0 + nb * 16 + col;
            xih[(size_t)m * 1024 + n] = acc[nb][r] + b_ih[n] + b_hh[n];
        }
}

// ---------------------------------------------------------------------------
// One LSTM step: gates = xih_t + h_prev @ w_hh^T, then c/h update.
__global__ __launch_bounds__(256) void lstm_step(
    const float* __restrict__ xih_t, const float* __restrict__ w_hh,
    const float* __restrict__ h_prev, const float* __restrict__ c_prev,
    float* __restrict__ h_new, float* __restrict__ c_new) {
    __shared__ float As[32][33];
    __shared__ float Ws[4][32][33];
    const int b0 = blockIdx.x * 32, j0 = blockIdx.y * 32;
    const int tid = threadIdx.x, tj = tid % 16, tb = tid / 16;
    float acc[4][2][2] = {};
    for (int k0 = 0; k0 < kH; k0 += 32) {
        for (int i = tid; i < 32 * 32; i += 256) {
            int r = i / 32, c = i % 32;
            As[r][c] = h_prev[(size_t)(b0 + r) * kH + k0 + c];
        }
        for (int i = tid; i < 4 * 32 * 32; i += 256) {
            int g = i / 1024, rem = i % 1024, r = rem / 32, c = rem % 32;
            Ws[g][r][c] = w_hh[(size_t)(g * kH + j0 + r) * kH + k0 + c];
        }
        __syncthreads();
#pragma unroll
        for (int kk = 0; kk < 32; ++kk) {
            float a0 = As[tb * 2 + 0][kk], a1 = As[tb * 2 + 1][kk];
#pragma unroll
            for (int g = 0; g < 4; ++g) {
                float w0 = Ws[g][tj * 2 + 0][kk], w1 = Ws[g][tj * 2 + 1][kk];
                acc[g][0][0] += a0 * w0; acc[g][0][1] += a0 * w1;
                acc[g][1][0] += a1 * w0; acc[g][1][1] += a1 * w1;
            }
        }
        __syncthreads();
    }
#pragma unroll
    for (int bb = 0; bb < 2; ++bb)
#pragma unroll
        for (int jj = 0; jj < 2; ++jj) {
            int b = b0 + tb * 2 + bb, j = j0 + tj * 2 + jj;
            float gi = acc[0][bb][jj] + xih_t[(size_t)b * 1024 + 0 * kH + j];
            float gf = acc[1][bb][jj] + xih_t[(size_t)b * 1024 + 1 * kH + j];
            float gg = acc[2][bb][jj] + xih_t[(size_t)b * 1024 + 2 * kH + j];
            float go = acc[3][bb][jj] + xih_t[(size_t)b * 1024 + 3 * kH + j];
            float i_ = 1.f / (1.f + expf(-gi));
            float f_ = 1.f / (1.f + expf(-gf));
            float g_ = tanhf(gg);
            float o_ = 1.f / (1.f + expf(-go));
            float c = f_ * c_prev[(size_t)b * kH + j] + i_ * g_;
            c_new[(size_t)b * kH + j] = c;
            h_new[(size_t)b * kH + j] = o_ * tanhf(c);
        }
}

__global__ void bias_relu(const float* __restrict__ acc, const float* __restrict__ bias,
                          float* __restrict__ out, int M, int N) {
    int i = blockIdx.x * blockDim.x + threadIdx.x;
    if (i < M * N) {
        int n = i % N;
        out[i] = fmaxf(acc[i] + bias[n], 0.f);
    }
}

// ---------------------------------------------------------------------------
// MFMA tap-pair fused conv1(3->16) + conv2(16->16), 3x3, pad 1, no act between.
// One block = one sample x one 8-row output slab. Both convs use the SAME
// decomposition: K=32 MFMA covers tap-pair p (k<16 -> tap 2p, k>=16 -> tap 2p+1);
// A[o][k] holds the weights (zeros for c>=Cin or tap 9), B read from channel-
// contiguous LDS [row][col][ch16] (32B col stride, 16B-aligned b128 reads).
// Zero padding (image border AND conv2's padding of conv1 output) comes from
// the LDS memset: invalid rows are simply skipped.
constexpr int ICH = 16;   // img_s channel stride (bf16)
constexpr int MCH = 16;   // mid_s channel stride (bf16)

__global__ __launch_bounds__(256) void conv_fused_mfma(
    const float* __restrict__ img,     // (B,3,64,64)
    const float* __restrict__ all_w,   // (B,2768)
    __bf16* __restrict__ out) {        // (B,16,64,64) bf16
    const int b = blockIdx.y;
    const int y0 = blockIdx.x * 8;
    __shared__ __align__(16) __bf16 w1a[5 * 16 * 32];         // [pair][o][k]
    __shared__ __align__(16) __bf16 w2a[5 * 16 * 32];         // [pair][o][k]
    __shared__ float bias_s[32];                              // conv1 | conv2 bias
    __shared__ __align__(16) __bf16 img_s[12 * 66 * ICH];     // rows gy=y0-2..y0+9
    __shared__ __align__(16) __bf16 mid_s[10 * 66 * MCH];     // rows gy=y0-1..y0+8

    const int tid = threadIdx.x, lane = tid & 63, wave = tid >> 6;
    const float* wb = all_w + (size_t)b * kTotalW;

    // ---- phase A0: memset both LDS tiles (halo zeros + pad channels), weights ----
    for (int i = tid; i < 12 * 66 * ICH / 8; i += 256)
        ((uint4*)img_s)[i] = make_uint4(0u, 0u, 0u, 0u);
    for (int i = tid; i < 10 * 66 * MCH / 8; i += 256)
        ((uint4*)mid_s)[i] = make_uint4(0u, 0u, 0u, 0u);
    for (int i = tid; i < 2560; i += 256) {      // w1a: k=half*16+c, t=2p+half
        int p = i >> 9, rem = i & 511, o = rem >> 5, k = rem & 31;
        int half = k >> 4, c = k & 15, t = 2 * p + half;
        w1a[i] = (__bf16)((c < 3 && t < 9) ? wb[o * 27 + c * 9 + t] : 0.f);
    }
    for (int i = tid; i < 2560; i += 256) {      // w2a
        int p = i >> 9, rem = i & 511, o = rem >> 5, k = rem & 31;
        int half = k >> 4, c = k & 15, t = 2 * p + half;
        w2a[i] = (__bf16)((t < 9) ? wb[448 + (o * 16 + c) * 9 + t] : 0.f);
    }
    if (tid < 16) bias_s[tid] = wb[432 + tid];
    else if (tid < 32) bias_s[tid] = wb[2752 + (tid - 16)];
    __syncthreads();

    // ---- phase A1: fill real image pixels (coalesced global reads) ----
    for (int i = tid; i < 3 * 12 * 64; i += 256) {
        int c = i / 768, rem = i - c * 768, r = rem >> 6, x = rem & 63;
        int gy = y0 - 2 + r;
        if (gy >= 0 && gy < 64)
            img_s[(r * 66 + (x + 1)) * ICH + c] =
                (__bf16)img[(((size_t)b * 3 + c) << 12) + (gy << 6) + x];
    }
    __syncthreads();

    // per-lane fragment constants (shared by both convs)
    const int n = lane & 15, half = lane >> 5;
    const int c0 = ((lane >> 4) & 1) * 8, o0 = (lane >> 4) * 4;
    int dy_[5], dx_[5];
#pragma unroll
    for (int p = 0; p < 5; ++p) {
        int t = 2 * p + half;
        dy_[p] = (t < 9) ? t / 3 : 0;
        dx_[p] = (t < 9) ? t % 3 : 0;
    }
    bf16x8 a1[5], a2[5];
#pragma unroll
    for (int p = 0; p < 5; ++p) {
        a1[p] = *(const bf16x8*)&w1a[p * 512 + n * 32 + (lane >> 4) * 8];
        a2[p] = *(const bf16x8*)&w2a[p * 512 + n * 32 + (lane >> 4) * 8];
    }

    // ---- phase B: conv1, 40 tiles (10 mid-rows x 4 x-tiles), 10 per wave ----
#pragma unroll
    for (int ti = 0; ti < 10; ++ti) {
        int tile = wave * 10 + ti;
        int rr = tile >> 2, xt = (tile & 3) * 16;
        int gy = y0 - 1 + rr;                    // mid row's global y
        if (gy >= 0 && gy < 64) {                // else: stays zero (conv2's padding)
            floatx4 acc = {};
#pragma unroll
            for (int p = 0; p < 5; ++p) {
                bf16x8 bfr = *(const bf16x8*)
                    &img_s[((rr + dy_[p]) * 66 + (xt + n + dx_[p])) * ICH + c0];
                acc = __builtin_amdgcn_mfma_f32_16x16x32_bf16(a1[p], bfr, acc, 0, 0, 0);
            }
            union { short4 s4; __bf16 h[4]; } u;
#pragma unroll
            for (int q = 0; q < 4; ++q) u.h[q] = (__bf16)(acc[q] + bias_s[o0 + q]);
            *(short4*)&mid_s[(rr * 66 + (xt + n + 1)) * MCH + o0] = u.s4;
        }
    }
    __syncthreads();

    // ---- phase C: conv2, 32 tiles (8 rows x 4 x-tiles), 8 per wave ----
#pragma unroll
    for (int ti = 0; ti < 8; ++ti) {
        int tile = wave * 8 + ti;
        int rr = tile >> 2, xt = (tile & 3) * 16;
        floatx4 acc = {};
#pragma unroll
        for (int p = 0; p < 5; ++p) {
            bf16x8 bfr = *(const bf16x8*)
                &mid_s[((rr + dy_[p]) * 66 + (xt + n + dx_[p])) * MCH + c0];
            acc = __builtin_amdgcn_mfma_f32_16x16x32_bf16(a2[p], bfr, acc, 0, 0, 0);
        }
        int gy = y0 + rr, gx = xt + n;
#pragma unroll
        for (int q = 0; q < 4; ++q)
            out[(((size_t)b * 16 + o0 + q) * 64 + gy) * 64 + gx] =
                (__bf16)(acc[q] + bias_s[16 + o0 + q]);
    }
}

// ---------------------------------------------------------------------------
// Fused lin2+lin3: out(256,2). grid B, block 64.
__global__ __launch_bounds__(64) void lin23(
    const float* __restrict__ l1out,
    const float* __restrict__ lw2, const float* __restrict__ lb2,
    const float* __restrict__ lw3, const float* __restrict__ lb3,
    float* __restrict__ out) {
    const int b = blockIdx.x, j = threadIdx.x;
    __shared__ float row[512];
    __shared__ float s[64];
    for (int i = j; i < 512; i += 64) row[i] = l1out[(size_t)b * 512 + i];
    __syncthreads();
    float acc = lb2[j];
    for (int k = 0; k < 512; ++k) acc += row[k] * lw2[(size_t)k * 64 + j];
    s[j] = fmaxf(acc, 0.f);
    __syncthreads();
    if (j < 2) {
        float o = lb3[j];
        for (int k = 0; k < 64; ++k) o += s[k] * lw3[(size_t)k * 2 + j];
        out[(size_t)b * 2 + j] = o;
    }
}

// ---------------------------------------------------------------------------
extern "C" void kernel_launch(void* const* d_in, const int* in_sizes, int n_in,
                              void* d_out, int out_size, void* d_ws, size_t ws_size,
                              hipStream_t stream) {
    const int* questions = (const int*)d_in[0];
    const float* images  = (const float*)d_in[1];
    const float* emb     = (const float*)d_in[2];
    const float* w_ih    = (const float*)d_in[3];
    const float* w_hh    = (const float*)d_in[4];
    const float* b_ih    = (const float*)d_in[5];
    const float* b_hh    = (const float*)d_in[6];
    const float* hw1     = (const float*)d_in[7];
    const float* hb1     = (const float*)d_in[8];
    const float* hw2     = (const float*)d_in[9];
    const float* hb2     = (const float*)d_in[10];
    const float* hw3     = (const float*)d_in[11];
    const float* hb3     = (const float*)d_in[12];
    const float* lw1     = (const float*)d_in[13];
    const float* lb1     = (const float*)d_in[14];
    const float* lw2     = (const float*)d_in[15];
    const float* lb2     = (const float*)d_in[16];
    const float* lw3     = (const float*)d_in[17];
    const float* lb3     = (const float*)d_in[18];
    float* out = (float*)d_out;

    char* ws = (char*)d_ws;
    size_t off = 0;
    auto alloc = [&](size_t nbytes) -> void* {
        void* p = (void*)(ws + off);
        off += (nbytes + 255) & ~(size_t)255;
        return p;
    };
    // big (64MB) timeline (single stream, strictly ordered):
    //   [0..20MB)  xih fp32            (dead after LSTM)
    //   [24..47MB) w3t bf16            (dead after hw3 MFMA GEMM)
    //   [0..32MB)  conv out bf16       (written by conv_fused_mfma, after both above dead)
    float*  big   = (float*)alloc(64ull << 20);
    __bf16* lw1t  = (__bf16*)alloc((size_t)512 * 65536 * 2);   // lw1^T bf16
    float*  hc0   = (float*)alloc(2 * kB * kH * sizeof(float));
    float*  hc1   = (float*)alloc(2 * kB * kH * sizeof(float));
    __bf16* w1t   = (__bf16*)alloc((size_t)1024 * 256 * 2);    // hw1^T bf16
    __bf16* w2t   = (__bf16*)alloc((size_t)4096 * 1024 * 2);   // hw2^T bf16
    __bf16* embb  = (__bf16*)alloc((size_t)10000 * kE * 2);    // emb bf16
    __bf16* w_ihb = (__bf16*)alloc((size_t)1024 * kE * 2);     // w_ih bf16 (already (N,K))
    __bf16* h0b   = (__bf16*)alloc((size_t)kB * kH * 2);
    __bf16* h1b   = (__bf16*)alloc((size_t)kB * 1024 * 2);
    __bf16* h2b   = (__bf16*)alloc((size_t)kB * 4096 * 2);
    // contiguous fp32 accumulators (zeroed in one kernel): hw1 | hw2 | hw3 | lin1
    float*  accz  = (float*)alloc((size_t)kB * (1024 + 4096 + 2768 + 512) * sizeof(float));
    float*  accA  = accz;
    float*  accB  = accA + (size_t)kB * 1024;
    float*  accC  = accB + (size_t)kB * 4096;
    float*  acc1  = accC + (size_t)kB * 2768;
    float*  allw  = (float*)alloc((size_t)kB * kTotalW * sizeof(float));
    float*  l1out = (float*)alloc((size_t)kB * 512 * sizeof(float));

    float*  xih    = big;
    __bf16* c2out  = (__bf16*)big;
    __bf16* w3t    = (__bf16*)((char*)big + (24ull << 20));    // 2768 x 4096 bf16
    float* hbuf[2] = {hc0, hc1};
    float* cbuf[2] = {hc0 + kB * kH, hc1 + kB * kH};

    const int nACC = kB * (1024 + 4096 + 2768 + 512);
    zero_f32<<<512, 256, 0, stream>>>(accz, nACC);
    zero_f32<<<256, 256, 0, stream>>>(hc0, 2 * kB * kH);       // h0=c0=0

    // weight converts/transposes (regions disjoint from their concurrent readers/writers)
    cvt_bf16<<<1280, 256, 0, stream>>>(emb, embb, 10000 * kE);
    cvt_bf16<<<128, 256, 0, stream>>>(w_ih, w_ihb, 1024 * kE);
    transpose_cvt<<<dim3(8, 32),   256, 0, stream>>>(hw1, w1t, 256, 1024);
    transpose_cvt<<<dim3(32, 128), 256, 0, stream>>>(hw2, w2t, 1024, 4096);
    transpose_cvt<<<dim3(128, 87), 256, 0, stream>>>(hw3, w3t, 4096, 2768);
    transpose_cvt<<<dim3(2048, 16), 256, 0, stream>>>(lw1, lw1t, 65536, 512);

    // 1) xih = emb[q] @ w_ih^T + b_ih + b_hh via MFMA, laid out (S,B,4H)
    xih_mfma<<<dim3(80, 16), 256, 0, stream>>>(questions, embb, w_ihb, b_ih, b_hh, xih);

    // 2) 20 LSTM steps (ping-pong h/c)
    for (int t = 0; t < kS; ++t) {
        lstm_step<<<dim3(8, 8), 256, 0, stream>>>(
            xih + (size_t)t * kB * 1024, w_hh,
            hbuf[t & 1], cbuf[t & 1], hbuf[(t + 1) & 1], cbuf[(t + 1) & 1]);
    }
    const float* hfin = hbuf[0];  // t=19 writes buffer 0
    cvt_bf16<<<64, 256, 0, stream>>>(hfin, h0b, kB * kH);

    // 3) hyper-MLP via bf16 MFMA split-K GEMMs (128x128 tile, global_load_lds)
    mfma128<<<dim3(2, 8, 4),  256, 0, stream>>>(h0b, w1t, accA, 256, 1024, 256, 64);
    ep_lrelu_bf16<<<1024, 256, 0, stream>>>(accA, hb1, h1b, 256, 1024);
    mfma128<<<dim3(2, 32, 4), 256, 0, stream>>>(h1b, w2t, accB, 256, 4096, 1024, 256);
    ep_lrelu_bf16<<<4096, 256, 0, stream>>>(accB, hb2, h2b, 256, 4096);
    mfma128<<<dim3(2, 22, 8), 256, 0, stream>>>(h2b, w3t, accC, 256, 2768, 4096, 512);
    ep_bias_f32<<<2768, 256, 0, stream>>>(accC, hb3, allw, 256, 2768);

    // 4) fused conv1+conv2 via MFMA tap-pair implicit GEMM -> bf16
    conv_fused_mfma<<<dim3(8, 256), 256, 0, stream>>>(images, allw, c2out);

    // 5) lin1 via bf16 MFMA split-K: 256x512, K=65536, splits=64 (512 blocks, 16 iters)
    mfma128<<<dim3(2, 4, 64), 256, 0, stream>>>(c2out, lw1t, acc1, 256, 512, 65536, 1024);
    bias_relu<<<512, 256, 0, stream>>>(acc1, lb1, l1out, 256, 512);

    // 6) lin2+lin3 fused -> out (256,2)
    lin23<<<256, 64, 0, stream>>>(l1out, lw2, lb2, lw3, lb3, out);
}